// Round 5
// baseline (741.884 us; speedup 1.0000x reference)
//
#include <hip/hip_runtime.h>
#include <hip/hip_bf16.h>

#define N_NODES 100000
#define N_EDGES 1600000
#define DIM 128
#define N_GRAPHS 512
#define N_CLASSES 10
#define SCAN_CHUNK 1024
#define N_CHUNKS ((N_NODES + SCAN_CHUNK - 1) / SCAN_CHUNK)   // 98

// bucketed CSR build: 128 nodes per bucket
#define NB 782            // ceil(100000 / 128)
#define BCAP 2560         // mean 2048, std ~45 -> 11 sigma slack

typedef __attribute__((ext_vector_type(8))) short short8;
typedef __attribute__((ext_vector_type(4))) float floatx4;

__device__ __forceinline__ uint bfround(float f) {   // fp32 -> bf16 bits (RNE)
    uint u = __builtin_bit_cast(uint, f);
    return (u + 0x7fffu + ((u >> 16) & 1u)) >> 16;
}
__device__ __forceinline__ float bflo(uint u) { return __builtin_bit_cast(float, u << 16); }
__device__ __forceinline__ float bfhi(uint u) { return __builtin_bit_cast(float, u & 0xffff0000u); }
__device__ __forceinline__ float bf2f(ushort u) { return __builtin_bit_cast(float, (uint)u << 16); }

__device__ __forceinline__ void addrow(float* a, uint4 v) {
    a[0] += bflo(v.x); a[1] += bfhi(v.x);
    a[2] += bflo(v.y); a[3] += bfhi(v.y);
    a[4] += bflo(v.z); a[5] += bfhi(v.z);
    a[6] += bflo(v.w); a[7] += bfhi(v.w);
}

// ---------------- dtype conversion ----------------

__global__ void k_cvt_x(const float* __restrict__ x, ushort* __restrict__ xb, int n4) {
    int i = blockIdx.x * blockDim.x + threadIdx.x;
    int stride = gridDim.x * blockDim.x;
    for (; i < n4; i += stride) {
        floatx4 v = *(const floatx4*)(x + (size_t)i * 4);
        ushort4 o;
        o.x = (ushort)bfround(v.x);
        o.y = (ushort)bfround(v.y);
        o.z = (ushort)bfround(v.z);
        o.w = (ushort)bfround(v.w);
        *(ushort4*)(xb + (size_t)i * 4) = o;
    }
}

struct WPtrs { const float* w[6]; };

// W [K=128][N=128] fp32 -> Wt [N][K] bf16, 6 matrices in one launch (grid 6*64)
__global__ __launch_bounds__(256) void k_cvt_w(WPtrs wp, ushort* __restrict__ Wt) {
    int m = blockIdx.x >> 6;
    int idx = (blockIdx.x & 63) * 256 + threadIdx.x;   // 0..16383
    int n = idx >> 7, k = idx & 127;
    Wt[(size_t)m * 16384 + idx] = (ushort)bfround(wp.w[m][k * 128 + n]);
}

// ---------------- CSR build (bucketed) ----------------

__global__ void k_zero(int* __restrict__ p, int n) {
    int i = blockIdx.x * blockDim.x + threadIdx.x;
    int stride = gridDim.x * blockDim.x;
    for (; i < n; i += stride) p[i] = 0;
}

// phase A: scatter edges into per-128-node buckets; entry = src | (dst&127)<<17
__global__ void k_bucket(const int* __restrict__ srcv, const int* __restrict__ dstv,
                         int* __restrict__ bcnt, uint* __restrict__ bdata) {
    int i = blockIdx.x * blockDim.x + threadIdx.x;
    int stride = gridDim.x * blockDim.x;
    for (; i < N_EDGES; i += stride) {
        int s = srcv[i], d = dstv[i];
        int b = d >> 7;
        int p = atomicAdd(&bcnt[b], 1);
        if (p < BCAP) bdata[(size_t)b * BCAP + p] = (uint)s | ((uint)(d & 127) << 17);
    }
}

// phase B1: per-bucket LDS histogram -> counts (no global atomics; each node in
// exactly one bucket)
__global__ __launch_bounds__(256) void k_bcount(const int* __restrict__ bcnt,
                                                const uint* __restrict__ bdata,
                                                int* __restrict__ counts) {
    __shared__ int cnt[128];
    int b = blockIdx.x, tid = threadIdx.x;
    if (tid < 128) cnt[tid] = 0;
    __syncthreads();
    int n = min(bcnt[b], BCAP);
    const uint* bd = bdata + (size_t)b * BCAP;
    for (int i = tid; i < n; i += 256) atomicAdd(&cnt[bd[i] >> 17], 1);
    __syncthreads();
    int node = (b << 7) + tid;
    if (tid < 128 && node < N_NODES) counts[node] = cnt[tid];
}

// phase B2: per-bucket fill; LDS cursors seeded from row_ptr; col writes land in
// one contiguous ~8KB region per bucket
__global__ __launch_bounds__(256) void k_bfill(const int* __restrict__ bcnt,
                                               const uint* __restrict__ bdata,
                                               const int* __restrict__ row_ptr,
                                               int* __restrict__ col) {
    __shared__ int cur[128];
    int b = blockIdx.x, tid = threadIdx.x;
    int node = (b << 7) + tid;
    if (tid < 128 && node < N_NODES) cur[tid] = row_ptr[node];
    __syncthreads();
    int n = min(bcnt[b], BCAP);
    const uint* bd = bdata + (size_t)b * BCAP;
    for (int i = tid; i < n; i += 256) {
        uint e = bd[i];
        int p = atomicAdd(&cur[e >> 17], 1);
        col[p] = (int)(e & 0x1FFFFu);
    }
}

__global__ __launch_bounds__(256) void k_chunk_reduce(const int* __restrict__ counts,
                                                      int* __restrict__ chunk_sums) {
    int base = blockIdx.x * SCAN_CHUNK;
    int tid = threadIdx.x;
    int s = 0;
    for (int i = tid; i < SCAN_CHUNK; i += 256) {
        int idx = base + i;
        if (idx < N_NODES) s += counts[idx];
    }
    __shared__ int red[256];
    red[tid] = s;
    __syncthreads();
    for (int off = 128; off > 0; off >>= 1) {
        if (tid < off) red[tid] += red[tid + off];
        __syncthreads();
    }
    if (tid == 0) chunk_sums[blockIdx.x] = red[0];
}

// parallel exclusive scan of N_CHUNKS (<=128) chunk sums
__global__ __launch_bounds__(128) void k_scan_chunks(int* __restrict__ chunk_sums,
                                                     int* __restrict__ row_ptr) {
    __shared__ int s[128];
    int tid = threadIdx.x;
    int v = (tid < N_CHUNKS) ? chunk_sums[tid] : 0;
    s[tid] = v;
    __syncthreads();
    for (int off = 1; off < 128; off <<= 1) {
        int t = (tid >= off) ? s[tid - off] : 0;
        __syncthreads();
        s[tid] += t;
        __syncthreads();
    }
    if (tid < N_CHUNKS) chunk_sums[tid] = s[tid] - v;   // exclusive
    if (tid == N_CHUNKS - 1) row_ptr[N_NODES] = s[tid];
}

__global__ __launch_bounds__(256) void k_chunk_scan(const int* __restrict__ counts,
                                                    const int* __restrict__ chunk_sums,
                                                    int* __restrict__ row_ptr) {
    int base = blockIdx.x * SCAN_CHUNK;
    int tid = threadIdx.x;
    int i0 = base + tid * 4;
    int v[4];
    int s = 0;
    #pragma unroll
    for (int j = 0; j < 4; j++) {
        int idx = i0 + j;
        v[j] = (idx < N_NODES) ? counts[idx] : 0;
        s += v[j];
    }
    __shared__ int sc[256];
    sc[tid] = s;
    __syncthreads();
    for (int off = 1; off < 256; off <<= 1) {
        int t = (tid >= off) ? sc[tid - off] : 0;
        __syncthreads();
        sc[tid] += t;
        __syncthreads();
    }
    int excl = sc[tid] - s + chunk_sums[blockIdx.x];
    #pragma unroll
    for (int j = 0; j < 4; j++) {
        int idx = i0 + j;
        if (idx < N_NODES) row_ptr[idx] = excl;
        excl += v[j];
    }
}

// ---------------- GIN aggregation (bf16 rows, fp32 accum, 4-edge ILP) ------
// one wave per node; uniform trip counts, all shfl executed by all 64 lanes
// with clamped source-lane indices (R3 lesson: masked-lane bpermute is UB).
__global__ __launch_bounds__(256) void k_agg(const uint4* __restrict__ xr,
                                             const int* __restrict__ row_ptr,
                                             const int* __restrict__ col,
                                             uint4* __restrict__ hr) {
    int node = (blockIdx.x << 2) + (threadIdx.x >> 6);
    if (node >= N_NODES) return;
    int lane = threadIdx.x & 63;
    int grp = lane >> 4;
    int l16 = lane & 15;

    float acc[8];
    if (grp == 0) {
        uint4 sv = xr[(size_t)node * 16 + l16];    // self term (eps=0)
        acc[0] = bflo(sv.x); acc[1] = bfhi(sv.x);
        acc[2] = bflo(sv.y); acc[3] = bfhi(sv.y);
        acc[4] = bflo(sv.z); acc[5] = bfhi(sv.z);
        acc[6] = bflo(sv.w); acc[7] = bfhi(sv.w);
    } else {
        #pragma unroll
        for (int i = 0; i < 8; i++) acc[i] = 0.f;
    }

    int b = row_ptr[node], e = row_ptr[node + 1];
    for (int j0 = b; j0 < e; j0 += 64) {
        int rem = e - j0;
        int chunk = rem < 64 ? rem : 64;
        int myidx = (lane < chunk) ? col[j0 + lane] : 0;
        int iters = (chunk + 15) >> 4;          // wave-uniform
        for (int f = 0; f < iters; f++) {
            int p = (f << 4) + grp;
            int s0 = __shfl(myidx, (p      < chunk) ? p      : 0);
            int s1 = __shfl(myidx, (p + 4  < chunk) ? p + 4  : 0);
            int s2 = __shfl(myidx, (p + 8  < chunk) ? p + 8  : 0);
            int s3 = __shfl(myidx, (p + 12 < chunk) ? p + 12 : 0);
            uint4 v0 = xr[(size_t)s0 * 16 + l16];   // 4 loads in flight
            uint4 v1 = xr[(size_t)s1 * 16 + l16];
            uint4 v2 = xr[(size_t)s2 * 16 + l16];
            uint4 v3 = xr[(size_t)s3 * 16 + l16];
            if (p < chunk)      addrow(acc, v0);
            if (p + 4 < chunk)  addrow(acc, v1);
            if (p + 8 < chunk)  addrow(acc, v2);
            if (p + 12 < chunk) addrow(acc, v3);
        }
    }

    #pragma unroll
    for (int i = 0; i < 8; i++) {
        acc[i] += __shfl_xor(acc[i], 16);
        acc[i] += __shfl_xor(acc[i], 32);
    }

    if (grp == 0) {
        uint4 o;
        o.x = bfround(acc[0]) | (bfround(acc[1]) << 16);
        o.y = bfround(acc[2]) | (bfround(acc[3]) << 16);
        o.z = bfround(acc[4]) | (bfround(acc[5]) << 16);
        o.w = bfround(acc[6]) | (bfround(acc[7]) << 16);
        hr[(size_t)node * 16 + l16] = o;
    }
}

// ---------------- fused MFMA MLP ----------------
__device__ __forceinline__ int loff(int row, int byte) {
    return row * 256 + (byte ^ ((row & 7) << 4));
}

__global__ __launch_bounds__(256) void k_mlp(const ushort* __restrict__ hin,
                                             ushort* __restrict__ xout,
                                             const ushort* __restrict__ W1t,
                                             const float* __restrict__ b1,
                                             const ushort* __restrict__ W2t,
                                             const float* __restrict__ b2) {
    __shared__ alignas(16) char hT[64 * 256];
    __shared__ alignas(16) char tT[64 * 256];
    int tid = threadIdx.x;
    int lane = tid & 63;
    int wave = tid >> 6;
    int node0 = blockIdx.x * 64;
    int l15 = lane & 15;
    int lhi = lane >> 4;

    #pragma unroll
    for (int it = 0; it < 4; ++it) {
        int idx = it * 256 + tid;
        int row = idx >> 4;
        int cb = (idx & 15) * 16;
        int gn = node0 + row;
        floatx4 v = {0.f, 0.f, 0.f, 0.f};
        if (gn < N_NODES) v = *(const floatx4*)(hin + (size_t)gn * 128 + cb / 2);
        *(floatx4*)(hT + loff(row, cb)) = v;
    }
    __syncthreads();

    int ncol0 = wave * 32;
    short8 bf[4][2];
    #pragma unroll
    for (int ks = 0; ks < 4; ks++)
        #pragma unroll
        for (int nf = 0; nf < 2; nf++) {
            int nrow = ncol0 + nf * 16 + l15;
            bf[ks][nf] = *(const short8*)(W1t + nrow * 128 + ks * 32 + lhi * 8);
        }

    floatx4 acc[4][2];
    #pragma unroll
    for (int m = 0; m < 4; m++)
        #pragma unroll
        for (int nf = 0; nf < 2; nf++) {
            float bias = b1[ncol0 + nf * 16 + l15];
            acc[m][nf] = (floatx4){bias, bias, bias, bias};
        }

    #pragma unroll
    for (int ks = 0; ks < 4; ks++) {
        short8 af[4];
        #pragma unroll
        for (int m = 0; m < 4; m++)
            af[m] = *(const short8*)(hT + loff(m * 16 + l15, ks * 64 + lhi * 16));
        #pragma unroll
        for (int m = 0; m < 4; m++)
            #pragma unroll
            for (int nf = 0; nf < 2; nf++)
                acc[m][nf] = __builtin_amdgcn_mfma_f32_16x16x32_bf16(af[m], bf[ks][nf], acc[m][nf], 0, 0, 0);
    }
    #pragma unroll
    for (int m = 0; m < 4; m++)
        #pragma unroll
        for (int nf = 0; nf < 2; nf++) {
            int colb = (ncol0 + nf * 16 + l15) * 2;
            #pragma unroll
            for (int j = 0; j < 4; j++) {
                int row = m * 16 + lhi * 4 + j;
                float t = acc[m][nf][j];
                t = t > 0.f ? t : 0.f;
                *(ushort*)(tT + loff(row, colb)) = (ushort)bfround(t);
            }
        }
    __syncthreads();

    #pragma unroll
    for (int ks = 0; ks < 4; ks++)
        #pragma unroll
        for (int nf = 0; nf < 2; nf++) {
            int nrow = ncol0 + nf * 16 + l15;
            bf[ks][nf] = *(const short8*)(W2t + nrow * 128 + ks * 32 + lhi * 8);
        }
    #pragma unroll
    for (int m = 0; m < 4; m++)
        #pragma unroll
        for (int nf = 0; nf < 2; nf++) {
            float bias = b2[ncol0 + nf * 16 + l15];
            acc[m][nf] = (floatx4){bias, bias, bias, bias};
        }

    #pragma unroll
    for (int ks = 0; ks < 4; ks++) {
        short8 af[4];
        #pragma unroll
        for (int m = 0; m < 4; m++)
            af[m] = *(const short8*)(tT + loff(m * 16 + l15, ks * 64 + lhi * 16));
        #pragma unroll
        for (int m = 0; m < 4; m++)
            #pragma unroll
            for (int nf = 0; nf < 2; nf++)
                acc[m][nf] = __builtin_amdgcn_mfma_f32_16x16x32_bf16(af[m], bf[ks][nf], acc[m][nf], 0, 0, 0);
    }
    #pragma unroll
    for (int m = 0; m < 4; m++)
        #pragma unroll
        for (int nf = 0; nf < 2; nf++) {
            int colb = (ncol0 + nf * 16 + l15) * 2;
            #pragma unroll
            for (int j = 0; j < 4; j++) {
                int row = m * 16 + lhi * 4 + j;
                float t = acc[m][nf][j];
                t = t > 0.f ? t : 0.f;
                *(ushort*)(hT + loff(row, colb)) = (ushort)bfround(t);
            }
        }
    __syncthreads();
    #pragma unroll
    for (int it = 0; it < 4; ++it) {
        int idx = it * 256 + tid;
        int row = idx >> 4;
        int cb = (idx & 15) * 16;
        int gn = node0 + row;
        if (gn < N_NODES)
            *(floatx4*)(xout + (size_t)gn * 128 + cb / 2) = *(const floatx4*)(hT + loff(row, cb));
    }
}

// ---------------- global add pool (batch sorted) ----------------
__global__ __launch_bounds__(128) void k_pool(const ushort* __restrict__ x,
                                              const int* __restrict__ batch,
                                              float* __restrict__ pooled) {
    int g = blockIdx.x;
    int c = threadIdx.x;
    int lo = 0, hi = N_NODES;
    while (lo < hi) { int m = (lo + hi) >> 1; if (batch[m] < g) lo = m + 1; else hi = m; }
    int start = lo;
    hi = N_NODES;
    while (lo < hi) { int m = (lo + hi) >> 1; if (batch[m] < g + 1) lo = m + 1; else hi = m; }
    int end = lo;
    float acc = 0.f;
    for (int n = start; n < end; n++) acc += bf2f(x[(size_t)n * 128 + c]);
    pooled[g * 128 + c] = acc;
}

__global__ __launch_bounds__(64) void k_final(const float* __restrict__ pooled,
                                              const float* __restrict__ wl,
                                              const float* __restrict__ bl,
                                              float* __restrict__ out) {
    int g = blockIdx.x;
    int o = threadIdx.x;
    if (o >= N_CLASSES) return;
    float acc = bl[o];
    for (int k = 0; k < 128; k++) acc += pooled[g * 128 + k] * wl[k * N_CLASSES + o];
    out[g * N_CLASSES + o] = acc;
}

// ---------------- launch ----------------

extern "C" void kernel_launch(void* const* d_in, const int* in_sizes, int n_in,
                              void* d_out, int out_size, void* d_ws, size_t ws_size,
                              hipStream_t stream) {
    const float* x0  = (const float*)d_in[0];
    const int* ei    = (const int*)d_in[1];
    const int* batch = (const int*)d_in[2];
    const float* W1[3] = {(const float*)d_in[3], (const float*)d_in[7],  (const float*)d_in[11]};
    const float* B1[3] = {(const float*)d_in[4], (const float*)d_in[8],  (const float*)d_in[12]};
    const float* W2[3] = {(const float*)d_in[5], (const float*)d_in[9],  (const float*)d_in[13]};
    const float* B2[3] = {(const float*)d_in[6], (const float*)d_in[10], (const float*)d_in[14]};
    const float* wl = (const float*)d_in[15];
    const float* bl = (const float*)d_in[16];
    float* out = (float*)d_out;

    const int* srcv = ei;
    const int* dstv = ei + N_EDGES;

    // workspace layout
    char* w = (char*)d_ws;
    ushort* xb = (ushort*)w;                                   // N*128 bf16 (25.6MB)
    ushort* hb = xb + (size_t)N_NODES * DIM;                   // N*128 bf16 (25.6MB)
    ushort* wt = hb + (size_t)N_NODES * DIM;                   // 6*128*128 bf16
    float* pooled = (float*)(wt + 6 * 128 * 128);              // 512*128 f32
    int* row_ptr = (int*)(pooled + N_GRAPHS * DIM);            // N+1
    int* counts  = row_ptr + (N_NODES + 2);                    // N
    int* colidx  = counts + N_NODES;                           // E (6.4MB)
    int* chunk_sums = colidx + N_EDGES;                        // 128
    int* bcnt    = chunk_sums + 128;                           // NB
    uint* bdata  = (uint*)(bcnt + ((NB + 3) & ~3));            // NB*BCAP (8MB)

    // ---- dtype conversion ----
    hipLaunchKernelGGL(k_cvt_x, dim3(2048), dim3(256), 0, stream, x0, xb, N_NODES * DIM / 4);
    WPtrs wp;
    wp.w[0] = W1[0]; wp.w[1] = W2[0]; wp.w[2] = W1[1];
    wp.w[3] = W2[1]; wp.w[4] = W1[2]; wp.w[5] = W2[2];
    hipLaunchKernelGGL(k_cvt_w, dim3(6 * 64), dim3(256), 0, stream, wp, wt);

    // ---- CSR build (bucketed) ----
    hipLaunchKernelGGL(k_zero, dim3(4), dim3(256), 0, stream, bcnt, NB);
    hipLaunchKernelGGL(k_bucket, dim3(2048), dim3(256), 0, stream, srcv, dstv, bcnt, bdata);
    hipLaunchKernelGGL(k_bcount, dim3(NB), dim3(256), 0, stream, bcnt, bdata, counts);
    hipLaunchKernelGGL(k_chunk_reduce, dim3(N_CHUNKS), dim3(256), 0, stream, counts, chunk_sums);
    hipLaunchKernelGGL(k_scan_chunks, dim3(1), dim3(128), 0, stream, chunk_sums, row_ptr);
    hipLaunchKernelGGL(k_chunk_scan, dim3(N_CHUNKS), dim3(256), 0, stream, counts, chunk_sums, row_ptr);
    hipLaunchKernelGGL(k_bfill, dim3(NB), dim3(256), 0, stream, bcnt, bdata, row_ptr, colidx);

    // ---- 3 GIN layers: agg (xb -> hb), mlp (hb -> xb) ----
    dim3 aggGrid((N_NODES + 3) / 4), aggBlk(256);
    dim3 mlpGrid((N_NODES + 63) / 64), mlpBlk(256);
    for (int l = 0; l < 3; l++) {
        hipLaunchKernelGGL(k_agg, aggGrid, aggBlk, 0, stream,
                           (const uint4*)xb, row_ptr, colidx, (uint4*)hb);
        hipLaunchKernelGGL(k_mlp, mlpGrid, mlpBlk, 0, stream,
                           hb, xb, wt + (size_t)(2 * l) * 16384, B1[l],
                           wt + (size_t)(2 * l + 1) * 16384, B2[l]);
    }

    // ---- pool + final ----
    hipLaunchKernelGGL(k_pool, dim3(N_GRAPHS), dim3(128), 0, stream, xb, batch, pooled);
    hipLaunchKernelGGL(k_final, dim3(N_GRAPHS), dim3(64), 0, stream, pooled, wl, bl, out);
}

// Round 6
// 496.871 us; speedup vs baseline: 1.4931x; 1.4931x over previous
//
#include <hip/hip_runtime.h>
#include <hip/hip_bf16.h>

#define N_NODES 100000
#define N_EDGES 1600000
#define DIM 128
#define N_GRAPHS 512
#define N_CLASSES 10
#define SCAN_CHUNK 1024
#define N_CHUNKS ((N_NODES + SCAN_CHUNK - 1) / SCAN_CHUNK)   // 98

// bucketed CSR build: 128 nodes per bucket, 32 stripes per bucket
#define NB 782            // ceil(100000 / 128)
#define NS 32             // stripes (contention: 1.6M/(782*32) = 64 per counter)
#define SCAP 128          // per-segment cap: Poisson(64), 8 sigma over 25K segments

typedef __attribute__((ext_vector_type(8))) short short8;
typedef __attribute__((ext_vector_type(4))) float floatx4;

__device__ __forceinline__ uint bfround(float f) {   // fp32 -> bf16 bits (RNE)
    uint u = __builtin_bit_cast(uint, f);
    return (u + 0x7fffu + ((u >> 16) & 1u)) >> 16;
}
__device__ __forceinline__ float bflo(uint u) { return __builtin_bit_cast(float, u << 16); }
__device__ __forceinline__ float bfhi(uint u) { return __builtin_bit_cast(float, u & 0xffff0000u); }
__device__ __forceinline__ float bf2f(ushort u) { return __builtin_bit_cast(float, (uint)u << 16); }

__device__ __forceinline__ void addrow(float* a, uint4 v) {
    a[0] += bflo(v.x); a[1] += bfhi(v.x);
    a[2] += bflo(v.y); a[3] += bfhi(v.y);
    a[4] += bflo(v.z); a[5] += bfhi(v.z);
    a[6] += bflo(v.w); a[7] += bfhi(v.w);
}

// ---------------- dtype conversion ----------------

__global__ void k_cvt_x(const float* __restrict__ x, ushort* __restrict__ xb, int n4) {
    int i = blockIdx.x * blockDim.x + threadIdx.x;
    int stride = gridDim.x * blockDim.x;
    for (; i < n4; i += stride) {
        floatx4 v = *(const floatx4*)(x + (size_t)i * 4);
        ushort4 o;
        o.x = (ushort)bfround(v.x);
        o.y = (ushort)bfround(v.y);
        o.z = (ushort)bfround(v.z);
        o.w = (ushort)bfround(v.w);
        *(ushort4*)(xb + (size_t)i * 4) = o;
    }
}

struct WPtrs { const float* w[6]; };

// W [K=128][N=128] fp32 -> Wt [N][K] bf16, 6 matrices in one launch (grid 6*64)
__global__ __launch_bounds__(256) void k_cvt_w(WPtrs wp, ushort* __restrict__ Wt) {
    int m = blockIdx.x >> 6;
    int idx = (blockIdx.x & 63) * 256 + threadIdx.x;   // 0..16383
    int n = idx >> 7, k = idx & 127;
    Wt[(size_t)m * 16384 + idx] = (ushort)bfround(wp.w[m][k * 128 + n]);
}

// ---------------- CSR build (bucketed, striped) ----------------

__global__ void k_zero(int* __restrict__ p, int n) {
    int i = blockIdx.x * blockDim.x + threadIdx.x;
    int stride = gridDim.x * blockDim.x;
    for (; i < n; i += stride) p[i] = 0;
}

// phase A: scatter edges into (bucket, stripe) segments; entry = src | (dst&127)<<17
// stripe fixed per thread; scnt stripe-major so a bucket's 32 counters sit on
// different cache lines (same-address atomic chains run in parallel).
__global__ void k_bucket(const int* __restrict__ srcv, const int* __restrict__ dstv,
                         int* __restrict__ scnt, uint* __restrict__ sdata) {
    int t = blockIdx.x * blockDim.x + threadIdx.x;
    int stride = gridDim.x * blockDim.x;
    int s = t & (NS - 1);
    for (int i = t; i < N_EDGES; i += stride) {
        int sr = srcv[i], d = dstv[i];
        int seg = s * NB + (d >> 7);
        int p = atomicAdd(&scnt[seg], 1);
        if (p < SCAP) sdata[(size_t)seg * SCAP + p] = (uint)sr | ((uint)(d & 127) << 17);
    }
}

// phase B1: per-bucket LDS histogram over its 32 segments -> counts
__global__ __launch_bounds__(256) void k_bcount(const int* __restrict__ scnt,
                                                const uint* __restrict__ sdata,
                                                int* __restrict__ counts) {
    __shared__ int cnt[128];
    int b = blockIdx.x, tid = threadIdx.x;
    if (tid < 128) cnt[tid] = 0;
    __syncthreads();
    for (int s = 0; s < NS; s++) {
        int seg = s * NB + b;
        int n = min(scnt[seg], SCAP);
        const uint* bd = sdata + (size_t)seg * SCAP;
        for (int i = tid; i < n; i += 256) atomicAdd(&cnt[bd[i] >> 17], 1);
    }
    __syncthreads();
    int node = (b << 7) + tid;
    if (tid < 128 && node < N_NODES) counts[node] = cnt[tid];
}

// phase B2: per-bucket fill; LDS cursors seeded from row_ptr; col writes land in
// one contiguous ~8KB region per bucket (written by this block only)
__global__ __launch_bounds__(256) void k_bfill(const int* __restrict__ scnt,
                                               const uint* __restrict__ sdata,
                                               const int* __restrict__ row_ptr,
                                               int* __restrict__ col) {
    __shared__ int cur[128];
    int b = blockIdx.x, tid = threadIdx.x;
    int node = (b << 7) + tid;
    if (tid < 128 && node < N_NODES) cur[tid] = row_ptr[node];
    __syncthreads();
    for (int s = 0; s < NS; s++) {
        int seg = s * NB + b;
        int n = min(scnt[seg], SCAP);
        const uint* bd = sdata + (size_t)seg * SCAP;
        for (int i = tid; i < n; i += 256) {
            uint e = bd[i];
            int p = atomicAdd(&cur[e >> 17], 1);
            col[p] = (int)(e & 0x1FFFFu);
        }
    }
}

__global__ __launch_bounds__(256) void k_chunk_reduce(const int* __restrict__ counts,
                                                      int* __restrict__ chunk_sums) {
    int base = blockIdx.x * SCAN_CHUNK;
    int tid = threadIdx.x;
    int s = 0;
    for (int i = tid; i < SCAN_CHUNK; i += 256) {
        int idx = base + i;
        if (idx < N_NODES) s += counts[idx];
    }
    __shared__ int red[256];
    red[tid] = s;
    __syncthreads();
    for (int off = 128; off > 0; off >>= 1) {
        if (tid < off) red[tid] += red[tid + off];
        __syncthreads();
    }
    if (tid == 0) chunk_sums[blockIdx.x] = red[0];
}

// parallel exclusive scan of N_CHUNKS (<=128) chunk sums
__global__ __launch_bounds__(128) void k_scan_chunks(int* __restrict__ chunk_sums,
                                                     int* __restrict__ row_ptr) {
    __shared__ int s[128];
    int tid = threadIdx.x;
    int v = (tid < N_CHUNKS) ? chunk_sums[tid] : 0;
    s[tid] = v;
    __syncthreads();
    for (int off = 1; off < 128; off <<= 1) {
        int t = (tid >= off) ? s[tid - off] : 0;
        __syncthreads();
        s[tid] += t;
        __syncthreads();
    }
    if (tid < N_CHUNKS) chunk_sums[tid] = s[tid] - v;   // exclusive
    if (tid == N_CHUNKS - 1) row_ptr[N_NODES] = s[tid];
}

__global__ __launch_bounds__(256) void k_chunk_scan(const int* __restrict__ counts,
                                                    const int* __restrict__ chunk_sums,
                                                    int* __restrict__ row_ptr) {
    int base = blockIdx.x * SCAN_CHUNK;
    int tid = threadIdx.x;
    int i0 = base + tid * 4;
    int v[4];
    int s = 0;
    #pragma unroll
    for (int j = 0; j < 4; j++) {
        int idx = i0 + j;
        v[j] = (idx < N_NODES) ? counts[idx] : 0;
        s += v[j];
    }
    __shared__ int sc[256];
    sc[tid] = s;
    __syncthreads();
    for (int off = 1; off < 256; off <<= 1) {
        int t = (tid >= off) ? sc[tid - off] : 0;
        __syncthreads();
        sc[tid] += t;
        __syncthreads();
    }
    int excl = sc[tid] - s + chunk_sums[blockIdx.x];
    #pragma unroll
    for (int j = 0; j < 4; j++) {
        int idx = i0 + j;
        if (idx < N_NODES) row_ptr[idx] = excl;
        excl += v[j];
    }
}

// ---------------- GIN aggregation (bf16 rows, fp32 accum, 4-edge ILP) ------
// one wave per node; uniform trip counts, all shfl executed by all 64 lanes
// with clamped source-lane indices (R3 lesson: masked-lane bpermute is UB).
__global__ __launch_bounds__(256) void k_agg(const uint4* __restrict__ xr,
                                             const int* __restrict__ row_ptr,
                                             const int* __restrict__ col,
                                             uint4* __restrict__ hr) {
    int node = (blockIdx.x << 2) + (threadIdx.x >> 6);
    if (node >= N_NODES) return;
    int lane = threadIdx.x & 63;
    int grp = lane >> 4;
    int l16 = lane & 15;

    float acc[8];
    if (grp == 0) {
        uint4 sv = xr[(size_t)node * 16 + l16];    // self term (eps=0)
        acc[0] = bflo(sv.x); acc[1] = bfhi(sv.x);
        acc[2] = bflo(sv.y); acc[3] = bfhi(sv.y);
        acc[4] = bflo(sv.z); acc[5] = bfhi(sv.z);
        acc[6] = bflo(sv.w); acc[7] = bfhi(sv.w);
    } else {
        #pragma unroll
        for (int i = 0; i < 8; i++) acc[i] = 0.f;
    }

    int b = row_ptr[node], e = row_ptr[node + 1];
    for (int j0 = b; j0 < e; j0 += 64) {
        int rem = e - j0;
        int chunk = rem < 64 ? rem : 64;
        int myidx = (lane < chunk) ? col[j0 + lane] : 0;
        int iters = (chunk + 15) >> 4;          // wave-uniform
        for (int f = 0; f < iters; f++) {
            int p = (f << 4) + grp;
            int s0 = __shfl(myidx, (p      < chunk) ? p      : 0);
            int s1 = __shfl(myidx, (p + 4  < chunk) ? p + 4  : 0);
            int s2 = __shfl(myidx, (p + 8  < chunk) ? p + 8  : 0);
            int s3 = __shfl(myidx, (p + 12 < chunk) ? p + 12 : 0);
            uint4 v0 = xr[(size_t)s0 * 16 + l16];   // 4 loads in flight
            uint4 v1 = xr[(size_t)s1 * 16 + l16];
            uint4 v2 = xr[(size_t)s2 * 16 + l16];
            uint4 v3 = xr[(size_t)s3 * 16 + l16];
            if (p < chunk)      addrow(acc, v0);
            if (p + 4 < chunk)  addrow(acc, v1);
            if (p + 8 < chunk)  addrow(acc, v2);
            if (p + 12 < chunk) addrow(acc, v3);
        }
    }

    #pragma unroll
    for (int i = 0; i < 8; i++) {
        acc[i] += __shfl_xor(acc[i], 16);
        acc[i] += __shfl_xor(acc[i], 32);
    }

    if (grp == 0) {
        uint4 o;
        o.x = bfround(acc[0]) | (bfround(acc[1]) << 16);
        o.y = bfround(acc[2]) | (bfround(acc[3]) << 16);
        o.z = bfround(acc[4]) | (bfround(acc[5]) << 16);
        o.w = bfround(acc[6]) | (bfround(acc[7]) << 16);
        hr[(size_t)node * 16 + l16] = o;
    }
}

// ---------------- fused MFMA MLP ----------------
__device__ __forceinline__ int loff(int row, int byte) {
    return row * 256 + (byte ^ ((row & 7) << 4));
}

__global__ __launch_bounds__(256) void k_mlp(const ushort* __restrict__ hin,
                                             ushort* __restrict__ xout,
                                             const ushort* __restrict__ W1t,
                                             const float* __restrict__ b1,
                                             const ushort* __restrict__ W2t,
                                             const float* __restrict__ b2) {
    __shared__ alignas(16) char hT[64 * 256];
    __shared__ alignas(16) char tT[64 * 256];
    int tid = threadIdx.x;
    int lane = tid & 63;
    int wave = tid >> 6;
    int node0 = blockIdx.x * 64;
    int l15 = lane & 15;
    int lhi = lane >> 4;

    #pragma unroll
    for (int it = 0; it < 4; ++it) {
        int idx = it * 256 + tid;
        int row = idx >> 4;
        int cb = (idx & 15) * 16;
        int gn = node0 + row;
        floatx4 v = {0.f, 0.f, 0.f, 0.f};
        if (gn < N_NODES) v = *(const floatx4*)(hin + (size_t)gn * 128 + cb / 2);
        *(floatx4*)(hT + loff(row, cb)) = v;
    }
    __syncthreads();

    int ncol0 = wave * 32;
    short8 bf[4][2];
    #pragma unroll
    for (int ks = 0; ks < 4; ks++)
        #pragma unroll
        for (int nf = 0; nf < 2; nf++) {
            int nrow = ncol0 + nf * 16 + l15;
            bf[ks][nf] = *(const short8*)(W1t + nrow * 128 + ks * 32 + lhi * 8);
        }

    floatx4 acc[4][2];
    #pragma unroll
    for (int m = 0; m < 4; m++)
        #pragma unroll
        for (int nf = 0; nf < 2; nf++) {
            float bias = b1[ncol0 + nf * 16 + l15];
            acc[m][nf] = (floatx4){bias, bias, bias, bias};
        }

    #pragma unroll
    for (int ks = 0; ks < 4; ks++) {
        short8 af[4];
        #pragma unroll
        for (int m = 0; m < 4; m++)
            af[m] = *(const short8*)(hT + loff(m * 16 + l15, ks * 64 + lhi * 16));
        #pragma unroll
        for (int m = 0; m < 4; m++)
            #pragma unroll
            for (int nf = 0; nf < 2; nf++)
                acc[m][nf] = __builtin_amdgcn_mfma_f32_16x16x32_bf16(af[m], bf[ks][nf], acc[m][nf], 0, 0, 0);
    }
    #pragma unroll
    for (int m = 0; m < 4; m++)
        #pragma unroll
        for (int nf = 0; nf < 2; nf++) {
            int colb = (ncol0 + nf * 16 + l15) * 2;
            #pragma unroll
            for (int j = 0; j < 4; j++) {
                int row = m * 16 + lhi * 4 + j;
                float t = acc[m][nf][j];
                t = t > 0.f ? t : 0.f;
                *(ushort*)(tT + loff(row, colb)) = (ushort)bfround(t);
            }
        }
    __syncthreads();

    #pragma unroll
    for (int ks = 0; ks < 4; ks++)
        #pragma unroll
        for (int nf = 0; nf < 2; nf++) {
            int nrow = ncol0 + nf * 16 + l15;
            bf[ks][nf] = *(const short8*)(W2t + nrow * 128 + ks * 32 + lhi * 8);
        }
    #pragma unroll
    for (int m = 0; m < 4; m++)
        #pragma unroll
        for (int nf = 0; nf < 2; nf++) {
            float bias = b2[ncol0 + nf * 16 + l15];
            acc[m][nf] = (floatx4){bias, bias, bias, bias};
        }

    #pragma unroll
    for (int ks = 0; ks < 4; ks++) {
        short8 af[4];
        #pragma unroll
        for (int m = 0; m < 4; m++)
            af[m] = *(const short8*)(tT + loff(m * 16 + l15, ks * 64 + lhi * 16));
        #pragma unroll
        for (int m = 0; m < 4; m++)
            #pragma unroll
            for (int nf = 0; nf < 2; nf++)
                acc[m][nf] = __builtin_amdgcn_mfma_f32_16x16x32_bf16(af[m], bf[ks][nf], acc[m][nf], 0, 0, 0);
    }
    #pragma unroll
    for (int m = 0; m < 4; m++)
        #pragma unroll
        for (int nf = 0; nf < 2; nf++) {
            int colb = (ncol0 + nf * 16 + l15) * 2;
            #pragma unroll
            for (int j = 0; j < 4; j++) {
                int row = m * 16 + lhi * 4 + j;
                float t = acc[m][nf][j];
                t = t > 0.f ? t : 0.f;
                *(ushort*)(hT + loff(row, colb)) = (ushort)bfround(t);
            }
        }
    __syncthreads();
    #pragma unroll
    for (int it = 0; it < 4; ++it) {
        int idx = it * 256 + tid;
        int row = idx >> 4;
        int cb = (idx & 15) * 16;
        int gn = node0 + row;
        if (gn < N_NODES)
            *(floatx4*)(xout + (size_t)gn * 128 + cb / 2) = *(const floatx4*)(hT + loff(row, cb));
    }
}

// ---------------- global add pool (batch sorted) ----------------
__global__ __launch_bounds__(128) void k_pool(const ushort* __restrict__ x,
                                              const int* __restrict__ batch,
                                              float* __restrict__ pooled) {
    int g = blockIdx.x;
    int c = threadIdx.x;
    int lo = 0, hi = N_NODES;
    while (lo < hi) { int m = (lo + hi) >> 1; if (batch[m] < g) lo = m + 1; else hi = m; }
    int start = lo;
    hi = N_NODES;
    while (lo < hi) { int m = (lo + hi) >> 1; if (batch[m] < g + 1) lo = m + 1; else hi = m; }
    int end = lo;
    float acc = 0.f;
    for (int n = start; n < end; n++) acc += bf2f(x[(size_t)n * 128 + c]);
    pooled[g * 128 + c] = acc;
}

__global__ __launch_bounds__(64) void k_final(const float* __restrict__ pooled,
                                              const float* __restrict__ wl,
                                              const float* __restrict__ bl,
                                              float* __restrict__ out) {
    int g = blockIdx.x;
    int o = threadIdx.x;
    if (o >= N_CLASSES) return;
    float acc = bl[o];
    for (int k = 0; k < 128; k++) acc += pooled[g * 128 + k] * wl[k * N_CLASSES + o];
    out[g * N_CLASSES + o] = acc;
}

// ---------------- launch ----------------

extern "C" void kernel_launch(void* const* d_in, const int* in_sizes, int n_in,
                              void* d_out, int out_size, void* d_ws, size_t ws_size,
                              hipStream_t stream) {
    const float* x0  = (const float*)d_in[0];
    const int* ei    = (const int*)d_in[1];
    const int* batch = (const int*)d_in[2];
    const float* W1[3] = {(const float*)d_in[3], (const float*)d_in[7],  (const float*)d_in[11]};
    const float* B1[3] = {(const float*)d_in[4], (const float*)d_in[8],  (const float*)d_in[12]};
    const float* W2[3] = {(const float*)d_in[5], (const float*)d_in[9],  (const float*)d_in[13]};
    const float* B2[3] = {(const float*)d_in[6], (const float*)d_in[10], (const float*)d_in[14]};
    const float* wl = (const float*)d_in[15];
    const float* bl = (const float*)d_in[16];
    float* out = (float*)d_out;

    const int* srcv = ei;
    const int* dstv = ei + N_EDGES;

    // workspace layout
    char* w = (char*)d_ws;
    ushort* xb = (ushort*)w;                                   // N*128 bf16 (25.6MB)
    ushort* hb = xb + (size_t)N_NODES * DIM;                   // N*128 bf16 (25.6MB)
    ushort* wt = hb + (size_t)N_NODES * DIM;                   // 6*128*128 bf16
    float* pooled = (float*)(wt + 6 * 128 * 128);              // 512*128 f32
    int* row_ptr = (int*)(pooled + N_GRAPHS * DIM);            // N+1
    int* counts  = row_ptr + (N_NODES + 2);                    // N
    int* colidx  = counts + N_NODES;                           // E (6.4MB)
    int* chunk_sums = colidx + N_EDGES;                        // 128
    int* scnt    = chunk_sums + 128;                           // NB*NS (100KB)
    uint* sdata  = (uint*)(scnt + ((NB * NS + 3) & ~3));       // NB*NS*SCAP (12.8MB)

    // ---- dtype conversion ----
    hipLaunchKernelGGL(k_cvt_x, dim3(2048), dim3(256), 0, stream, x0, xb, N_NODES * DIM / 4);
    WPtrs wp;
    wp.w[0] = W1[0]; wp.w[1] = W2[0]; wp.w[2] = W1[1];
    wp.w[3] = W2[1]; wp.w[4] = W1[2]; wp.w[5] = W2[2];
    hipLaunchKernelGGL(k_cvt_w, dim3(6 * 64), dim3(256), 0, stream, wp, wt);

    // ---- CSR build (bucketed, striped) ----
    hipLaunchKernelGGL(k_zero, dim3(32), dim3(256), 0, stream, scnt, NB * NS);
    hipLaunchKernelGGL(k_bucket, dim3(2048), dim3(256), 0, stream, srcv, dstv, scnt, sdata);
    hipLaunchKernelGGL(k_bcount, dim3(NB), dim3(256), 0, stream, scnt, sdata, counts);
    hipLaunchKernelGGL(k_chunk_reduce, dim3(N_CHUNKS), dim3(256), 0, stream, counts, chunk_sums);
    hipLaunchKernelGGL(k_scan_chunks, dim3(1), dim3(128), 0, stream, chunk_sums, row_ptr);
    hipLaunchKernelGGL(k_chunk_scan, dim3(N_CHUNKS), dim3(256), 0, stream, counts, chunk_sums, row_ptr);
    hipLaunchKernelGGL(k_bfill, dim3(NB), dim3(256), 0, stream, scnt, sdata, row_ptr, colidx);

    // ---- 3 GIN layers: agg (xb -> hb), mlp (hb -> xb) ----
    dim3 aggGrid((N_NODES + 3) / 4), aggBlk(256);
    dim3 mlpGrid((N_NODES + 63) / 64), mlpBlk(256);
    for (int l = 0; l < 3; l++) {
        hipLaunchKernelGGL(k_agg, aggGrid, aggBlk, 0, stream,
                           (const uint4*)xb, row_ptr, colidx, (uint4*)hb);
        hipLaunchKernelGGL(k_mlp, mlpGrid, mlpBlk, 0, stream,
                           hb, xb, wt + (size_t)(2 * l) * 16384, B1[l],
                           wt + (size_t)(2 * l + 1) * 16384, B2[l]);
    }

    // ---- pool + final ----
    hipLaunchKernelGGL(k_pool, dim3(N_GRAPHS), dim3(128), 0, stream, xb, batch, pooled);
    hipLaunchKernelGGL(k_final, dim3(N_GRAPHS), dim3(64), 0, stream, pooled, wl, bl, out);
}

// Round 7
// 396.987 us; speedup vs baseline: 1.8688x; 1.2516x over previous
//
#include <hip/hip_runtime.h>
#include <hip/hip_bf16.h>

#define N_NODES 100000
#define N_EDGES 1600000
#define DIM 128
#define N_GRAPHS 512
#define N_CLASSES 10
#define SCAN_CHUNK 1024

// 2-pass radix CSR build
#define NBK 782                 // buckets of 128 dst nodes
#define EB 8192                 // edges per histogram/scatter block
#define NEB 196                 // ceil(N_EDGES / EB)
#define HN (NBK * NEB)          // 153272 hist entries (bucket-major)
#define NCH_HIST ((HN + SCAN_CHUNK - 1) / SCAN_CHUNK)       // 150
#define NCH_CNT ((N_NODES + SCAN_CHUNK - 1) / SCAN_CHUNK)   // 98

typedef __attribute__((ext_vector_type(8))) short short8;
typedef __attribute__((ext_vector_type(4))) float floatx4;

__device__ __forceinline__ uint bfround(float f) {   // fp32 -> bf16 bits (RNE)
    uint u = __builtin_bit_cast(uint, f);
    return (u + 0x7fffu + ((u >> 16) & 1u)) >> 16;
}
__device__ __forceinline__ float bflo(uint u) { return __builtin_bit_cast(float, u << 16); }
__device__ __forceinline__ float bfhi(uint u) { return __builtin_bit_cast(float, u & 0xffff0000u); }
__device__ __forceinline__ float bf2f(ushort u) { return __builtin_bit_cast(float, (uint)u << 16); }

__device__ __forceinline__ void addrow(float* a, uint4 v) {
    a[0] += bflo(v.x); a[1] += bfhi(v.x);
    a[2] += bflo(v.y); a[3] += bfhi(v.y);
    a[4] += bflo(v.z); a[5] += bfhi(v.z);
    a[6] += bflo(v.w); a[7] += bfhi(v.w);
}

// ---------------- dtype conversion ----------------

__global__ void k_cvt_x(const float* __restrict__ x, ushort* __restrict__ xb, int n4) {
    int i = blockIdx.x * blockDim.x + threadIdx.x;
    int stride = gridDim.x * blockDim.x;
    for (; i < n4; i += stride) {
        floatx4 v = *(const floatx4*)(x + (size_t)i * 4);
        ushort4 o;
        o.x = (ushort)bfround(v.x);
        o.y = (ushort)bfround(v.y);
        o.z = (ushort)bfround(v.z);
        o.w = (ushort)bfround(v.w);
        *(ushort4*)(xb + (size_t)i * 4) = o;
    }
}

struct WPtrs { const float* w[6]; };

// W [K=128][N=128] fp32 -> Wt [N][K] bf16, 6 matrices in one launch (grid 6*64)
__global__ __launch_bounds__(256) void k_cvt_w(WPtrs wp, ushort* __restrict__ Wt) {
    int m = blockIdx.x >> 6;
    int idx = (blockIdx.x & 63) * 256 + threadIdx.x;   // 0..16383
    int n = idx >> 7, k = idx & 127;
    Wt[(size_t)m * 16384 + idx] = (ushort)bfround(wp.w[m][k * 128 + n]);
}

// ---------------- CSR build: 2-pass radix by bucket (dst>>7) ----------------
// All scatter writes are per-block contiguous; ZERO global atomics.

// pass 1: per-edge-block LDS histogram over 782 buckets -> hist[b*NEB + blk]
__global__ __launch_bounds__(256) void k_hist(const int* __restrict__ dstv,
                                              int* __restrict__ hist) {
    __shared__ int cnt[NBK];
    int blk = blockIdx.x, tid = threadIdx.x;
    for (int i = tid; i < NBK; i += 256) cnt[i] = 0;
    __syncthreads();
    int base = blk * EB;
    int end = min(base + EB, N_EDGES);
    for (int i = base + tid; i < end; i += 256) atomicAdd(&cnt[dstv[i] >> 7], 1);
    __syncthreads();
    for (int b = tid; b < NBK; b += 256) hist[b * NEB + blk] = cnt[b];
}

// ---- generic hierarchical exclusive scan (n <= 256*1024) ----
__global__ __launch_bounds__(256) void k_reduce(const int* __restrict__ src, int n,
                                                int* __restrict__ chunk_sums) {
    int base = blockIdx.x * SCAN_CHUNK;
    int tid = threadIdx.x;
    int s = 0;
    for (int i = tid; i < SCAN_CHUNK; i += 256) {
        int idx = base + i;
        if (idx < n) s += src[idx];
    }
    __shared__ int red[256];
    red[tid] = s;
    __syncthreads();
    for (int off = 128; off > 0; off >>= 1) {
        if (tid < off) red[tid] += red[tid + off];
        __syncthreads();
    }
    if (tid == 0) chunk_sums[blockIdx.x] = red[0];
}

__global__ __launch_bounds__(256) void k_scan_c(int* __restrict__ chunk_sums, int nch,
                                                int* __restrict__ total_out) {
    __shared__ int sm[256];
    int tid = threadIdx.x;
    int v = (tid < nch) ? chunk_sums[tid] : 0;
    sm[tid] = v;
    __syncthreads();
    for (int off = 1; off < 256; off <<= 1) {
        int t = (tid >= off) ? sm[tid - off] : 0;
        __syncthreads();
        sm[tid] += t;
        __syncthreads();
    }
    if (tid < nch) chunk_sums[tid] = sm[tid] - v;   // exclusive
    if (tid == 255) *total_out = sm[255];
}

// exclusive scan apply; safe in-place (src==dst): reads complete before barrier
__global__ __launch_bounds__(256) void k_apply(const int* __restrict__ src,
                                               const int* __restrict__ chunk_sums,
                                               int* __restrict__ dst, int n) {
    int base = blockIdx.x * SCAN_CHUNK;
    int tid = threadIdx.x;
    int i0 = base + tid * 4;
    int v[4];
    int s = 0;
    #pragma unroll
    for (int j = 0; j < 4; j++) {
        int idx = i0 + j;
        v[j] = (idx < n) ? src[idx] : 0;
        s += v[j];
    }
    __shared__ int sc[256];
    sc[tid] = s;
    __syncthreads();
    for (int off = 1; off < 256; off <<= 1) {
        int t = (tid >= off) ? sc[tid - off] : 0;
        __syncthreads();
        sc[tid] += t;
        __syncthreads();
    }
    int excl = sc[tid] - s + chunk_sums[blockIdx.x];
    #pragma unroll
    for (int j = 0; j < 4; j++) {
        int idx = i0 + j;
        if (idx < n) dst[idx] = excl;
        excl += v[j];
    }
}

// pass 2: scatter edges into bucket-sorted array. LDS cursor seeded with the
// global scanned base -> each (block,bucket) chunk is contiguous in memory,
// and adjacent blocks' chunks are adjacent. entry = src | (dst&127)<<17.
__global__ __launch_bounds__(256) void k_scatter(const int* __restrict__ srcv,
                                                 const int* __restrict__ dstv,
                                                 const int* __restrict__ hists,
                                                 uint* __restrict__ sorted) {
    __shared__ int cur[NBK];
    int blk = blockIdx.x, tid = threadIdx.x;
    for (int b = tid; b < NBK; b += 256) cur[b] = hists[b * NEB + blk];
    __syncthreads();
    int base = blk * EB;
    int end = min(base + EB, N_EDGES);
    for (int i = base + tid; i < end; i += 256) {
        int s = srcv[i], d = dstv[i];
        int p = atomicAdd(&cur[d >> 7], 1);
        sorted[p] = (uint)s | ((uint)(d & 127) << 17);
    }
}

// per-bucket node counts from sorted entries (contiguous read, LDS histogram)
__global__ __launch_bounds__(256) void k_bcount_s(const int* __restrict__ hists,
                                                  const uint* __restrict__ sorted,
                                                  int* __restrict__ counts) {
    __shared__ int cnt[128];
    int b = blockIdx.x, tid = threadIdx.x;
    if (tid < 128) cnt[tid] = 0;
    __syncthreads();
    int s0 = hists[b * NEB];
    int s1 = (b == NBK - 1) ? N_EDGES : hists[(b + 1) * NEB];
    for (int i = s0 + tid; i < s1; i += 256) atomicAdd(&cnt[(sorted[i] >> 17) & 127], 1);
    __syncthreads();
    int node = (b << 7) + tid;
    if (tid < 128 && node < N_NODES) counts[node] = cnt[tid];
}

// per-bucket fill of col: contiguous read; writes confined to this bucket's
// contiguous col region (~8KB) -> full-line writes
__global__ __launch_bounds__(256) void k_fill_s(const int* __restrict__ hists,
                                                const uint* __restrict__ sorted,
                                                const int* __restrict__ row_ptr,
                                                int* __restrict__ col) {
    __shared__ int cur[128];
    int b = blockIdx.x, tid = threadIdx.x;
    int node = (b << 7) + tid;
    if (tid < 128 && node < N_NODES) cur[tid] = row_ptr[node];
    __syncthreads();
    int s0 = hists[b * NEB];
    int s1 = (b == NBK - 1) ? N_EDGES : hists[(b + 1) * NEB];
    for (int i = s0 + tid; i < s1; i += 256) {
        uint e = sorted[i];
        int p = atomicAdd(&cur[(e >> 17) & 127], 1);
        col[p] = (int)(e & 0x1FFFFu);
    }
}

// ---------------- GIN aggregation (bf16 rows, fp32 accum, 4-edge ILP) ------
// one wave per node; uniform trip counts, all shfl executed by all 64 lanes
// with clamped source-lane indices (R3 lesson: masked-lane bpermute is UB).
__global__ __launch_bounds__(256) void k_agg(const uint4* __restrict__ xr,
                                             const int* __restrict__ row_ptr,
                                             const int* __restrict__ col,
                                             uint4* __restrict__ hr) {
    int node = (blockIdx.x << 2) + (threadIdx.x >> 6);
    if (node >= N_NODES) return;
    int lane = threadIdx.x & 63;
    int grp = lane >> 4;
    int l16 = lane & 15;

    float acc[8];
    if (grp == 0) {
        uint4 sv = xr[(size_t)node * 16 + l16];    // self term (eps=0)
        acc[0] = bflo(sv.x); acc[1] = bfhi(sv.x);
        acc[2] = bflo(sv.y); acc[3] = bfhi(sv.y);
        acc[4] = bflo(sv.z); acc[5] = bfhi(sv.z);
        acc[6] = bflo(sv.w); acc[7] = bfhi(sv.w);
    } else {
        #pragma unroll
        for (int i = 0; i < 8; i++) acc[i] = 0.f;
    }

    int b = row_ptr[node], e = row_ptr[node + 1];
    for (int j0 = b; j0 < e; j0 += 64) {
        int rem = e - j0;
        int chunk = rem < 64 ? rem : 64;
        int myidx = (lane < chunk) ? col[j0 + lane] : 0;
        int iters = (chunk + 15) >> 4;          // wave-uniform
        for (int f = 0; f < iters; f++) {
            int p = (f << 4) + grp;
            int s0 = __shfl(myidx, (p      < chunk) ? p      : 0);
            int s1 = __shfl(myidx, (p + 4  < chunk) ? p + 4  : 0);
            int s2 = __shfl(myidx, (p + 8  < chunk) ? p + 8  : 0);
            int s3 = __shfl(myidx, (p + 12 < chunk) ? p + 12 : 0);
            uint4 v0 = xr[(size_t)s0 * 16 + l16];   // 4 loads in flight
            uint4 v1 = xr[(size_t)s1 * 16 + l16];
            uint4 v2 = xr[(size_t)s2 * 16 + l16];
            uint4 v3 = xr[(size_t)s3 * 16 + l16];
            if (p < chunk)      addrow(acc, v0);
            if (p + 4 < chunk)  addrow(acc, v1);
            if (p + 8 < chunk)  addrow(acc, v2);
            if (p + 12 < chunk) addrow(acc, v3);
        }
    }

    #pragma unroll
    for (int i = 0; i < 8; i++) {
        acc[i] += __shfl_xor(acc[i], 16);
        acc[i] += __shfl_xor(acc[i], 32);
    }

    if (grp == 0) {
        uint4 o;
        o.x = bfround(acc[0]) | (bfround(acc[1]) << 16);
        o.y = bfround(acc[2]) | (bfround(acc[3]) << 16);
        o.z = bfround(acc[4]) | (bfround(acc[5]) << 16);
        o.w = bfround(acc[6]) | (bfround(acc[7]) << 16);
        hr[(size_t)node * 16 + l16] = o;
    }
}

// ---------------- fused MFMA MLP ----------------
__device__ __forceinline__ int loff(int row, int byte) {
    return row * 256 + (byte ^ ((row & 7) << 4));
}

__global__ __launch_bounds__(256) void k_mlp(const ushort* __restrict__ hin,
                                             ushort* __restrict__ xout,
                                             const ushort* __restrict__ W1t,
                                             const float* __restrict__ b1,
                                             const ushort* __restrict__ W2t,
                                             const float* __restrict__ b2) {
    __shared__ alignas(16) char hT[64 * 256];
    __shared__ alignas(16) char tT[64 * 256];
    int tid = threadIdx.x;
    int lane = tid & 63;
    int wave = tid >> 6;
    int node0 = blockIdx.x * 64;
    int l15 = lane & 15;
    int lhi = lane >> 4;

    #pragma unroll
    for (int it = 0; it < 4; ++it) {
        int idx = it * 256 + tid;
        int row = idx >> 4;
        int cb = (idx & 15) * 16;
        int gn = node0 + row;
        floatx4 v = {0.f, 0.f, 0.f, 0.f};
        if (gn < N_NODES) v = *(const floatx4*)(hin + (size_t)gn * 128 + cb / 2);
        *(floatx4*)(hT + loff(row, cb)) = v;
    }
    __syncthreads();

    int ncol0 = wave * 32;
    short8 bf[4][2];
    #pragma unroll
    for (int ks = 0; ks < 4; ks++)
        #pragma unroll
        for (int nf = 0; nf < 2; nf++) {
            int nrow = ncol0 + nf * 16 + l15;
            bf[ks][nf] = *(const short8*)(W1t + nrow * 128 + ks * 32 + lhi * 8);
        }

    floatx4 acc[4][2];
    #pragma unroll
    for (int m = 0; m < 4; m++)
        #pragma unroll
        for (int nf = 0; nf < 2; nf++) {
            float bias = b1[ncol0 + nf * 16 + l15];
            acc[m][nf] = (floatx4){bias, bias, bias, bias};
        }

    #pragma unroll
    for (int ks = 0; ks < 4; ks++) {
        short8 af[4];
        #pragma unroll
        for (int m = 0; m < 4; m++)
            af[m] = *(const short8*)(hT + loff(m * 16 + l15, ks * 64 + lhi * 16));
        #pragma unroll
        for (int m = 0; m < 4; m++)
            #pragma unroll
            for (int nf = 0; nf < 2; nf++)
                acc[m][nf] = __builtin_amdgcn_mfma_f32_16x16x32_bf16(af[m], bf[ks][nf], acc[m][nf], 0, 0, 0);
    }
    #pragma unroll
    for (int m = 0; m < 4; m++)
        #pragma unroll
        for (int nf = 0; nf < 2; nf++) {
            int colb = (ncol0 + nf * 16 + l15) * 2;
            #pragma unroll
            for (int j = 0; j < 4; j++) {
                int row = m * 16 + lhi * 4 + j;
                float t = acc[m][nf][j];
                t = t > 0.f ? t : 0.f;
                *(ushort*)(tT + loff(row, colb)) = (ushort)bfround(t);
            }
        }
    __syncthreads();

    #pragma unroll
    for (int ks = 0; ks < 4; ks++)
        #pragma unroll
        for (int nf = 0; nf < 2; nf++) {
            int nrow = ncol0 + nf * 16 + l15;
            bf[ks][nf] = *(const short8*)(W2t + nrow * 128 + ks * 32 + lhi * 8);
        }
    #pragma unroll
    for (int m = 0; m < 4; m++)
        #pragma unroll
        for (int nf = 0; nf < 2; nf++) {
            float bias = b2[ncol0 + nf * 16 + l15];
            acc[m][nf] = (floatx4){bias, bias, bias, bias};
        }

    #pragma unroll
    for (int ks = 0; ks < 4; ks++) {
        short8 af[4];
        #pragma unroll
        for (int m = 0; m < 4; m++)
            af[m] = *(const short8*)(tT + loff(m * 16 + l15, ks * 64 + lhi * 16));
        #pragma unroll
        for (int m = 0; m < 4; m++)
            #pragma unroll
            for (int nf = 0; nf < 2; nf++)
                acc[m][nf] = __builtin_amdgcn_mfma_f32_16x16x32_bf16(af[m], bf[ks][nf], acc[m][nf], 0, 0, 0);
    }
    #pragma unroll
    for (int m = 0; m < 4; m++)
        #pragma unroll
        for (int nf = 0; nf < 2; nf++) {
            int colb = (ncol0 + nf * 16 + l15) * 2;
            #pragma unroll
            for (int j = 0; j < 4; j++) {
                int row = m * 16 + lhi * 4 + j;
                float t = acc[m][nf][j];
                t = t > 0.f ? t : 0.f;
                *(ushort*)(hT + loff(row, colb)) = (ushort)bfround(t);
            }
        }
    __syncthreads();
    #pragma unroll
    for (int it = 0; it < 4; ++it) {
        int idx = it * 256 + tid;
        int row = idx >> 4;
        int cb = (idx & 15) * 16;
        int gn = node0 + row;
        if (gn < N_NODES)
            *(floatx4*)(xout + (size_t)gn * 128 + cb / 2) = *(const floatx4*)(hT + loff(row, cb));
    }
}

// ---------------- global add pool (batch sorted) ----------------
__global__ __launch_bounds__(128) void k_pool(const ushort* __restrict__ x,
                                              const int* __restrict__ batch,
                                              float* __restrict__ pooled) {
    int g = blockIdx.x;
    int c = threadIdx.x;
    int lo = 0, hi = N_NODES;
    while (lo < hi) { int m = (lo + hi) >> 1; if (batch[m] < g) lo = m + 1; else hi = m; }
    int start = lo;
    hi = N_NODES;
    while (lo < hi) { int m = (lo + hi) >> 1; if (batch[m] < g + 1) lo = m + 1; else hi = m; }
    int end = lo;
    float acc = 0.f;
    for (int n = start; n < end; n++) acc += bf2f(x[(size_t)n * 128 + c]);
    pooled[g * 128 + c] = acc;
}

__global__ __launch_bounds__(64) void k_final(const float* __restrict__ pooled,
                                              const float* __restrict__ wl,
                                              const float* __restrict__ bl,
                                              float* __restrict__ out) {
    int g = blockIdx.x;
    int o = threadIdx.x;
    if (o >= N_CLASSES) return;
    float acc = bl[o];
    for (int k = 0; k < 128; k++) acc += pooled[g * 128 + k] * wl[k * N_CLASSES + o];
    out[g * N_CLASSES + o] = acc;
}

// ---------------- launch ----------------

extern "C" void kernel_launch(void* const* d_in, const int* in_sizes, int n_in,
                              void* d_out, int out_size, void* d_ws, size_t ws_size,
                              hipStream_t stream) {
    const float* x0  = (const float*)d_in[0];
    const int* ei    = (const int*)d_in[1];
    const int* batch = (const int*)d_in[2];
    const float* W1[3] = {(const float*)d_in[3], (const float*)d_in[7],  (const float*)d_in[11]};
    const float* B1[3] = {(const float*)d_in[4], (const float*)d_in[8],  (const float*)d_in[12]};
    const float* W2[3] = {(const float*)d_in[5], (const float*)d_in[9],  (const float*)d_in[13]};
    const float* B2[3] = {(const float*)d_in[6], (const float*)d_in[10], (const float*)d_in[14]};
    const float* wl = (const float*)d_in[15];
    const float* bl = (const float*)d_in[16];
    float* out = (float*)d_out;

    const int* srcv = ei;
    const int* dstv = ei + N_EDGES;

    // workspace layout
    char* w = (char*)d_ws;
    ushort* xb = (ushort*)w;                                   // N*128 bf16 (25.6MB)
    ushort* hb = xb + (size_t)N_NODES * DIM;                   // N*128 bf16 (25.6MB)
    ushort* wt = hb + (size_t)N_NODES * DIM;                   // 6*128*128 bf16
    float* pooled = (float*)(wt + 6 * 128 * 128);              // 512*128 f32
    int* row_ptr = (int*)(pooled + N_GRAPHS * DIM);            // N+2
    int* counts  = row_ptr + (N_NODES + 2);                    // N
    int* colidx  = counts + N_NODES;                           // E (6.4MB)
    int* chunk_sums = colidx + N_EDGES;                        // 256
    int* hist    = chunk_sums + 256;                           // HN+1 (613KB)
    uint* sorted = (uint*)(hist + HN + 1);                     // E (6.4MB)

    // ---- dtype conversion ----
    hipLaunchKernelGGL(k_cvt_x, dim3(2048), dim3(256), 0, stream, x0, xb, N_NODES * DIM / 4);
    WPtrs wp;
    wp.w[0] = W1[0]; wp.w[1] = W2[0]; wp.w[2] = W1[1];
    wp.w[3] = W2[1]; wp.w[4] = W1[2]; wp.w[5] = W2[2];
    hipLaunchKernelGGL(k_cvt_w, dim3(6 * 64), dim3(256), 0, stream, wp, wt);

    // ---- CSR build: 2-pass radix ----
    hipLaunchKernelGGL(k_hist, dim3(NEB), dim3(256), 0, stream, dstv, hist);
    hipLaunchKernelGGL(k_reduce, dim3(NCH_HIST), dim3(256), 0, stream, hist, HN, chunk_sums);
    hipLaunchKernelGGL(k_scan_c, dim3(1), dim3(256), 0, stream, chunk_sums, NCH_HIST, hist + HN);
    hipLaunchKernelGGL(k_apply, dim3(NCH_HIST), dim3(256), 0, stream, hist, chunk_sums, hist, HN);
    hipLaunchKernelGGL(k_scatter, dim3(NEB), dim3(256), 0, stream, srcv, dstv, hist, sorted);
    hipLaunchKernelGGL(k_bcount_s, dim3(NBK), dim3(256), 0, stream, hist, sorted, counts);
    hipLaunchKernelGGL(k_reduce, dim3(NCH_CNT), dim3(256), 0, stream, counts, N_NODES, chunk_sums);
    hipLaunchKernelGGL(k_scan_c, dim3(1), dim3(256), 0, stream, chunk_sums, NCH_CNT, row_ptr + N_NODES);
    hipLaunchKernelGGL(k_apply, dim3(NCH_CNT), dim3(256), 0, stream, counts, chunk_sums, row_ptr, N_NODES);
    hipLaunchKernelGGL(k_fill_s, dim3(NBK), dim3(256), 0, stream, hist, sorted, row_ptr, colidx);

    // ---- 3 GIN layers: agg (xb -> hb), mlp (hb -> xb) ----
    dim3 aggGrid((N_NODES + 3) / 4), aggBlk(256);
    dim3 mlpGrid((N_NODES + 63) / 64), mlpBlk(256);
    for (int l = 0; l < 3; l++) {
        hipLaunchKernelGGL(k_agg, aggGrid, aggBlk, 0, stream,
                           (const uint4*)xb, row_ptr, colidx, (uint4*)hb);
        hipLaunchKernelGGL(k_mlp, mlpGrid, mlpBlk, 0, stream,
                           hb, xb, wt + (size_t)(2 * l) * 16384, B1[l],
                           wt + (size_t)(2 * l + 1) * 16384, B2[l]);
    }

    // ---- pool + final ----
    hipLaunchKernelGGL(k_pool, dim3(N_GRAPHS), dim3(128), 0, stream, xb, batch, pooled);
    hipLaunchKernelGGL(k_final, dim3(N_GRAPHS), dim3(64), 0, stream, pooled, wl, bl, out);
}

// Round 8
// 346.300 us; speedup vs baseline: 2.1423x; 1.1464x over previous
//
#include <hip/hip_runtime.h>
#include <hip/hip_bf16.h>

#define N_NODES 100000
#define N_EDGES 1600000
#define DIM 128
#define N_GRAPHS 512
#define N_CLASSES 10
#define SCAN_CHUNK 1024

// 2-pass radix CSR build
#define NBK 782                 // buckets of 128 dst nodes
#define EB 8192                 // edges per histogram/scatter block
#define NEB 196                 // ceil(N_EDGES / EB)
#define HN (NBK * NEB)          // 153272 hist entries (bucket-major)
#define NCH_HIST ((HN + SCAN_CHUNK - 1) / SCAN_CHUNK)       // 150
#define NCH_CNT ((N_NODES + SCAN_CHUNK - 1) / SCAN_CHUNK)   // 98

// node-parallel pool
#define POOL_CHUNK 128
#define NPB ((N_NODES + POOL_CHUNK - 1) / POOL_CHUNK)       // 782

typedef __attribute__((ext_vector_type(8))) short short8;
typedef __attribute__((ext_vector_type(4))) float floatx4;

__device__ __forceinline__ uint bfround(float f) {   // fp32 -> bf16 bits (RNE)
    uint u = __builtin_bit_cast(uint, f);
    return (u + 0x7fffu + ((u >> 16) & 1u)) >> 16;
}
__device__ __forceinline__ float bflo(uint u) { return __builtin_bit_cast(float, u << 16); }
__device__ __forceinline__ float bfhi(uint u) { return __builtin_bit_cast(float, u & 0xffff0000u); }
__device__ __forceinline__ float bf2f(ushort u) { return __builtin_bit_cast(float, (uint)u << 16); }

__device__ __forceinline__ void addrow(float* a, uint4 v) {
    a[0] += bflo(v.x); a[1] += bfhi(v.x);
    a[2] += bflo(v.y); a[3] += bfhi(v.y);
    a[4] += bflo(v.z); a[5] += bfhi(v.z);
    a[6] += bflo(v.w); a[7] += bfhi(v.w);
}

// ---------------- dtype conversion ----------------

__global__ void k_cvt_x(const float* __restrict__ x, ushort* __restrict__ xb, int n4) {
    int i = blockIdx.x * blockDim.x + threadIdx.x;
    int stride = gridDim.x * blockDim.x;
    for (; i < n4; i += stride) {
        floatx4 v = *(const floatx4*)(x + (size_t)i * 4);
        ushort4 o;
        o.x = (ushort)bfround(v.x);
        o.y = (ushort)bfround(v.y);
        o.z = (ushort)bfround(v.z);
        o.w = (ushort)bfround(v.w);
        *(ushort4*)(xb + (size_t)i * 4) = o;
    }
}

struct WPtrs { const float* w[6]; };

// W [K=128][N=128] fp32 -> Wt [N][K] bf16, 6 matrices in one launch (grid 6*64)
__global__ __launch_bounds__(256) void k_cvt_w(WPtrs wp, ushort* __restrict__ Wt) {
    int m = blockIdx.x >> 6;
    int idx = (blockIdx.x & 63) * 256 + threadIdx.x;   // 0..16383
    int n = idx >> 7, k = idx & 127;
    Wt[(size_t)m * 16384 + idx] = (ushort)bfround(wp.w[m][k * 128 + n]);
}

// ---------------- CSR build: 2-pass radix by bucket (dst>>7) ----------------
// All scatter writes are per-block contiguous; ZERO global atomics.

__global__ void k_zero(int* __restrict__ p, int n) {
    int i = blockIdx.x * blockDim.x + threadIdx.x;
    int stride = gridDim.x * blockDim.x;
    for (; i < n; i += stride) p[i] = 0;
}

// pass 1: per-edge-block LDS histogram over 782 buckets -> hist[b*NEB + blk]
__global__ __launch_bounds__(256) void k_hist(const int* __restrict__ dstv,
                                              int* __restrict__ hist) {
    __shared__ int cnt[NBK];
    int blk = blockIdx.x, tid = threadIdx.x;
    for (int i = tid; i < NBK; i += 256) cnt[i] = 0;
    __syncthreads();
    int base = blk * EB;
    int end = min(base + EB, N_EDGES);
    for (int i = base + tid; i < end; i += 256) atomicAdd(&cnt[dstv[i] >> 7], 1);
    __syncthreads();
    for (int b = tid; b < NBK; b += 256) hist[b * NEB + blk] = cnt[b];
}

// ---- generic hierarchical exclusive scan (n <= 256*1024) ----
__global__ __launch_bounds__(256) void k_reduce(const int* __restrict__ src, int n,
                                                int* __restrict__ chunk_sums) {
    int base = blockIdx.x * SCAN_CHUNK;
    int tid = threadIdx.x;
    int s = 0;
    for (int i = tid; i < SCAN_CHUNK; i += 256) {
        int idx = base + i;
        if (idx < n) s += src[idx];
    }
    __shared__ int red[256];
    red[tid] = s;
    __syncthreads();
    for (int off = 128; off > 0; off >>= 1) {
        if (tid < off) red[tid] += red[tid + off];
        __syncthreads();
    }
    if (tid == 0) chunk_sums[blockIdx.x] = red[0];
}

__global__ __launch_bounds__(256) void k_scan_c(int* __restrict__ chunk_sums, int nch,
                                                int* __restrict__ total_out) {
    __shared__ int sm[256];
    int tid = threadIdx.x;
    int v = (tid < nch) ? chunk_sums[tid] : 0;
    sm[tid] = v;
    __syncthreads();
    for (int off = 1; off < 256; off <<= 1) {
        int t = (tid >= off) ? sm[tid - off] : 0;
        __syncthreads();
        sm[tid] += t;
        __syncthreads();
    }
    if (tid < nch) chunk_sums[tid] = sm[tid] - v;   // exclusive
    if (tid == 255) *total_out = sm[255];
}

// exclusive scan apply; safe in-place (src==dst): reads complete before barrier
__global__ __launch_bounds__(256) void k_apply(const int* __restrict__ src,
                                               const int* __restrict__ chunk_sums,
                                               int* __restrict__ dst, int n) {
    int base = blockIdx.x * SCAN_CHUNK;
    int tid = threadIdx.x;
    int i0 = base + tid * 4;
    int v[4];
    int s = 0;
    #pragma unroll
    for (int j = 0; j < 4; j++) {
        int idx = i0 + j;
        v[j] = (idx < n) ? src[idx] : 0;
        s += v[j];
    }
    __shared__ int sc[256];
    sc[tid] = s;
    __syncthreads();
    for (int off = 1; off < 256; off <<= 1) {
        int t = (tid >= off) ? sc[tid - off] : 0;
        __syncthreads();
        sc[tid] += t;
        __syncthreads();
    }
    int excl = sc[tid] - s + chunk_sums[blockIdx.x];
    #pragma unroll
    for (int j = 0; j < 4; j++) {
        int idx = i0 + j;
        if (idx < n) dst[idx] = excl;
        excl += v[j];
    }
}

// pass 2: scatter edges into bucket-sorted array. LDS cursor seeded with the
// global scanned base -> each (block,bucket) chunk is contiguous in memory,
// and adjacent blocks' chunks are adjacent. entry = src | (dst&127)<<17.
__global__ __launch_bounds__(256) void k_scatter(const int* __restrict__ srcv,
                                                 const int* __restrict__ dstv,
                                                 const int* __restrict__ hists,
                                                 uint* __restrict__ sorted) {
    __shared__ int cur[NBK];
    int blk = blockIdx.x, tid = threadIdx.x;
    for (int b = tid; b < NBK; b += 256) cur[b] = hists[b * NEB + blk];
    __syncthreads();
    int base = blk * EB;
    int end = min(base + EB, N_EDGES);
    for (int i = base + tid; i < end; i += 256) {
        int s = srcv[i], d = dstv[i];
        int p = atomicAdd(&cur[d >> 7], 1);
        sorted[p] = (uint)s | ((uint)(d & 127) << 17);
    }
}

// per-bucket node counts from sorted entries (contiguous read, LDS histogram)
__global__ __launch_bounds__(256) void k_bcount_s(const int* __restrict__ hists,
                                                  const uint* __restrict__ sorted,
                                                  int* __restrict__ counts) {
    __shared__ int cnt[128];
    int b = blockIdx.x, tid = threadIdx.x;
    if (tid < 128) cnt[tid] = 0;
    __syncthreads();
    int s0 = hists[b * NEB];
    int s1 = (b == NBK - 1) ? N_EDGES : hists[(b + 1) * NEB];
    for (int i = s0 + tid; i < s1; i += 256) atomicAdd(&cnt[(sorted[i] >> 17) & 127], 1);
    __syncthreads();
    int node = (b << 7) + tid;
    if (tid < 128 && node < N_NODES) counts[node] = cnt[tid];
}

// per-bucket fill of col: contiguous read; writes confined to this bucket's
// contiguous col region (~8KB) -> full-line writes
__global__ __launch_bounds__(256) void k_fill_s(const int* __restrict__ hists,
                                                const uint* __restrict__ sorted,
                                                const int* __restrict__ row_ptr,
                                                int* __restrict__ col) {
    __shared__ int cur[128];
    int b = blockIdx.x, tid = threadIdx.x;
    int node = (b << 7) + tid;
    if (tid < 128 && node < N_NODES) cur[tid] = row_ptr[node];
    __syncthreads();
    int s0 = hists[b * NEB];
    int s1 = (b == NBK - 1) ? N_EDGES : hists[(b + 1) * NEB];
    for (int i = s0 + tid; i < s1; i += 256) {
        uint e = sorted[i];
        int p = atomicAdd(&cur[(e >> 17) & 127], 1);
        col[p] = (int)(e & 0x1FFFFu);
    }
}

// ---------------- GIN aggregation (bf16 rows, fp32 accum, 4-edge ILP) ------
// one wave per node; uniform trip counts, all shfl executed by all 64 lanes
// with clamped source-lane indices (R3 lesson: masked-lane bpermute is UB).
__global__ __launch_bounds__(256) void k_agg(const uint4* __restrict__ xr,
                                             const int* __restrict__ row_ptr,
                                             const int* __restrict__ col,
                                             uint4* __restrict__ hr) {
    int node = (blockIdx.x << 2) + (threadIdx.x >> 6);
    if (node >= N_NODES) return;
    int lane = threadIdx.x & 63;
    int grp = lane >> 4;
    int l16 = lane & 15;

    float acc[8];
    if (grp == 0) {
        uint4 sv = xr[(size_t)node * 16 + l16];    // self term (eps=0)
        acc[0] = bflo(sv.x); acc[1] = bfhi(sv.x);
        acc[2] = bflo(sv.y); acc[3] = bfhi(sv.y);
        acc[4] = bflo(sv.z); acc[5] = bfhi(sv.z);
        acc[6] = bflo(sv.w); acc[7] = bfhi(sv.w);
    } else {
        #pragma unroll
        for (int i = 0; i < 8; i++) acc[i] = 0.f;
    }

    int b = row_ptr[node], e = row_ptr[node + 1];
    for (int j0 = b; j0 < e; j0 += 64) {
        int rem = e - j0;
        int chunk = rem < 64 ? rem : 64;
        int myidx = (lane < chunk) ? col[j0 + lane] : 0;
        int iters = (chunk + 15) >> 4;          // wave-uniform
        for (int f = 0; f < iters; f++) {
            int p = (f << 4) + grp;
            int s0 = __shfl(myidx, (p      < chunk) ? p      : 0);
            int s1 = __shfl(myidx, (p + 4  < chunk) ? p + 4  : 0);
            int s2 = __shfl(myidx, (p + 8  < chunk) ? p + 8  : 0);
            int s3 = __shfl(myidx, (p + 12 < chunk) ? p + 12 : 0);
            uint4 v0 = xr[(size_t)s0 * 16 + l16];   // 4 loads in flight
            uint4 v1 = xr[(size_t)s1 * 16 + l16];
            uint4 v2 = xr[(size_t)s2 * 16 + l16];
            uint4 v3 = xr[(size_t)s3 * 16 + l16];
            if (p < chunk)      addrow(acc, v0);
            if (p + 4 < chunk)  addrow(acc, v1);
            if (p + 8 < chunk)  addrow(acc, v2);
            if (p + 12 < chunk) addrow(acc, v3);
        }
    }

    #pragma unroll
    for (int i = 0; i < 8; i++) {
        acc[i] += __shfl_xor(acc[i], 16);
        acc[i] += __shfl_xor(acc[i], 32);
    }

    if (grp == 0) {
        uint4 o;
        o.x = bfround(acc[0]) | (bfround(acc[1]) << 16);
        o.y = bfround(acc[2]) | (bfround(acc[3]) << 16);
        o.z = bfround(acc[4]) | (bfround(acc[5]) << 16);
        o.w = bfround(acc[6]) | (bfround(acc[7]) << 16);
        hr[(size_t)node * 16 + l16] = o;
    }
}

// ---------------- fused MFMA MLP ----------------
__device__ __forceinline__ int loff(int row, int byte) {
    return row * 256 + (byte ^ ((row & 7) << 4));
}

__global__ __launch_bounds__(256) void k_mlp(const ushort* __restrict__ hin,
                                             ushort* __restrict__ xout,
                                             const ushort* __restrict__ W1t,
                                             const float* __restrict__ b1,
                                             const ushort* __restrict__ W2t,
                                             const float* __restrict__ b2) {
    __shared__ alignas(16) char hT[64 * 256];
    __shared__ alignas(16) char tT[64 * 256];
    int tid = threadIdx.x;
    int lane = tid & 63;
    int wave = tid >> 6;
    int node0 = blockIdx.x * 64;
    int l15 = lane & 15;
    int lhi = lane >> 4;

    #pragma unroll
    for (int it = 0; it < 4; ++it) {
        int idx = it * 256 + tid;
        int row = idx >> 4;
        int cb = (idx & 15) * 16;
        int gn = node0 + row;
        floatx4 v = {0.f, 0.f, 0.f, 0.f};
        if (gn < N_NODES) v = *(const floatx4*)(hin + (size_t)gn * 128 + cb / 2);
        *(floatx4*)(hT + loff(row, cb)) = v;
    }
    __syncthreads();

    int ncol0 = wave * 32;
    short8 bf[4][2];
    #pragma unroll
    for (int ks = 0; ks < 4; ks++)
        #pragma unroll
        for (int nf = 0; nf < 2; nf++) {
            int nrow = ncol0 + nf * 16 + l15;
            bf[ks][nf] = *(const short8*)(W1t + nrow * 128 + ks * 32 + lhi * 8);
        }

    floatx4 acc[4][2];
    #pragma unroll
    for (int m = 0; m < 4; m++)
        #pragma unroll
        for (int nf = 0; nf < 2; nf++) {
            float bias = b1[ncol0 + nf * 16 + l15];
            acc[m][nf] = (floatx4){bias, bias, bias, bias};
        }

    #pragma unroll
    for (int ks = 0; ks < 4; ks++) {
        short8 af[4];
        #pragma unroll
        for (int m = 0; m < 4; m++)
            af[m] = *(const short8*)(hT + loff(m * 16 + l15, ks * 64 + lhi * 16));
        #pragma unroll
        for (int m = 0; m < 4; m++)
            #pragma unroll
            for (int nf = 0; nf < 2; nf++)
                acc[m][nf] = __builtin_amdgcn_mfma_f32_16x16x32_bf16(af[m], bf[ks][nf], acc[m][nf], 0, 0, 0);
    }
    #pragma unroll
    for (int m = 0; m < 4; m++)
        #pragma unroll
        for (int nf = 0; nf < 2; nf++) {
            int colb = (ncol0 + nf * 16 + l15) * 2;
            #pragma unroll
            for (int j = 0; j < 4; j++) {
                int row = m * 16 + lhi * 4 + j;
                float t = acc[m][nf][j];
                t = t > 0.f ? t : 0.f;
                *(ushort*)(tT + loff(row, colb)) = (ushort)bfround(t);
            }
        }
    __syncthreads();

    #pragma unroll
    for (int ks = 0; ks < 4; ks++)
        #pragma unroll
        for (int nf = 0; nf < 2; nf++) {
            int nrow = ncol0 + nf * 16 + l15;
            bf[ks][nf] = *(const short8*)(W2t + nrow * 128 + ks * 32 + lhi * 8);
        }
    #pragma unroll
    for (int m = 0; m < 4; m++)
        #pragma unroll
        for (int nf = 0; nf < 2; nf++) {
            float bias = b2[ncol0 + nf * 16 + l15];
            acc[m][nf] = (floatx4){bias, bias, bias, bias};
        }

    #pragma unroll
    for (int ks = 0; ks < 4; ks++) {
        short8 af[4];
        #pragma unroll
        for (int m = 0; m < 4; m++)
            af[m] = *(const short8*)(tT + loff(m * 16 + l15, ks * 64 + lhi * 16));
        #pragma unroll
        for (int m = 0; m < 4; m++)
            #pragma unroll
            for (int nf = 0; nf < 2; nf++)
                acc[m][nf] = __builtin_amdgcn_mfma_f32_16x16x32_bf16(af[m], bf[ks][nf], acc[m][nf], 0, 0, 0);
    }
    #pragma unroll
    for (int m = 0; m < 4; m++)
        #pragma unroll
        for (int nf = 0; nf < 2; nf++) {
            int colb = (ncol0 + nf * 16 + l15) * 2;
            #pragma unroll
            for (int j = 0; j < 4; j++) {
                int row = m * 16 + lhi * 4 + j;
                float t = acc[m][nf][j];
                t = t > 0.f ? t : 0.f;
                *(ushort*)(hT + loff(row, colb)) = (ushort)bfround(t);
            }
        }
    __syncthreads();
    #pragma unroll
    for (int it = 0; it < 4; ++it) {
        int idx = it * 256 + tid;
        int row = idx >> 4;
        int cb = (idx & 15) * 16;
        int gn = node0 + row;
        if (gn < N_NODES)
            *(floatx4*)(xout + (size_t)gn * 128 + cb / 2) = *(const floatx4*)(hT + loff(row, cb));
    }
}

// ---------------- global add pool (node-parallel, batch sorted) ----------------
// 782 blocks x 4 waves; wave w strides nodes n0+w, n0+w+4, ... Lane owns 2
// channels (uint = bf16x2). Running (graph, acc) flushed via f32 atomicAdd on
// graph change (~1-2 graphs per 128-node chunk since batch is sorted).
__global__ __launch_bounds__(256) void k_pool(const uint* __restrict__ x,
                                              const int* __restrict__ batch,
                                              float* __restrict__ pooled) {
    int n0 = blockIdx.x * POOL_CHUNK;
    int wave = threadIdx.x >> 6;
    int lane = threadIdx.x & 63;
    float a0 = 0.f, a1 = 0.f;
    int cur = -1;
    int endn = min(n0 + POOL_CHUNK, N_NODES);
    for (int n = n0 + wave; n < endn; n += 4) {
        int g = batch[n];                      // wave-uniform
        if (g != cur) {
            if (cur >= 0) {
                atomicAdd(&pooled[cur * 128 + lane * 2], a0);
                atomicAdd(&pooled[cur * 128 + lane * 2 + 1], a1);
            }
            cur = g; a0 = 0.f; a1 = 0.f;
        }
        uint v = x[(size_t)n * 64 + lane];     // 256B/row coalesced
        a0 += bflo(v); a1 += bfhi(v);
    }
    if (cur >= 0) {
        atomicAdd(&pooled[cur * 128 + lane * 2], a0);
        atomicAdd(&pooled[cur * 128 + lane * 2 + 1], a1);
    }
}

__global__ __launch_bounds__(64) void k_final(const float* __restrict__ pooled,
                                              const float* __restrict__ wl,
                                              const float* __restrict__ bl,
                                              float* __restrict__ out) {
    int g = blockIdx.x;
    int o = threadIdx.x;
    if (o >= N_CLASSES) return;
    float acc = bl[o];
    for (int k = 0; k < 128; k++) acc += pooled[g * 128 + k] * wl[k * N_CLASSES + o];
    out[g * N_CLASSES + o] = acc;
}

// ---------------- launch ----------------

extern "C" void kernel_launch(void* const* d_in, const int* in_sizes, int n_in,
                              void* d_out, int out_size, void* d_ws, size_t ws_size,
                              hipStream_t stream) {
    const float* x0  = (const float*)d_in[0];
    const int* ei    = (const int*)d_in[1];
    const int* batch = (const int*)d_in[2];
    const float* W1[3] = {(const float*)d_in[3], (const float*)d_in[7],  (const float*)d_in[11]};
    const float* B1[3] = {(const float*)d_in[4], (const float*)d_in[8],  (const float*)d_in[12]};
    const float* W2[3] = {(const float*)d_in[5], (const float*)d_in[9],  (const float*)d_in[13]};
    const float* B2[3] = {(const float*)d_in[6], (const float*)d_in[10], (const float*)d_in[14]};
    const float* wl = (const float*)d_in[15];
    const float* bl = (const float*)d_in[16];
    float* out = (float*)d_out;

    const int* srcv = ei;
    const int* dstv = ei + N_EDGES;

    // workspace layout
    char* w = (char*)d_ws;
    ushort* xb = (ushort*)w;                                   // N*128 bf16 (25.6MB)
    ushort* hb = xb + (size_t)N_NODES * DIM;                   // N*128 bf16 (25.6MB)
    ushort* wt = hb + (size_t)N_NODES * DIM;                   // 6*128*128 bf16
    float* pooled = (float*)(wt + 6 * 128 * 128);              // 512*128 f32
    int* row_ptr = (int*)(pooled + N_GRAPHS * DIM);            // N+2
    int* counts  = row_ptr + (N_NODES + 2);                    // N
    int* colidx  = counts + N_NODES;                           // E (6.4MB)
    int* chunk_sums = colidx + N_EDGES;                        // 256
    int* hist    = chunk_sums + 256;                           // HN+1 (613KB)
    uint* sorted = (uint*)(hist + HN + 1);                     // E (6.4MB)

    // ---- dtype conversion + pooled zero-init ----
    hipLaunchKernelGGL(k_cvt_x, dim3(2048), dim3(256), 0, stream, x0, xb, N_NODES * DIM / 4);
    WPtrs wp;
    wp.w[0] = W1[0]; wp.w[1] = W2[0]; wp.w[2] = W1[1];
    wp.w[3] = W2[1]; wp.w[4] = W1[2]; wp.w[5] = W2[2];
    hipLaunchKernelGGL(k_cvt_w, dim3(6 * 64), dim3(256), 0, stream, wp, wt);
    hipLaunchKernelGGL(k_zero, dim3(64), dim3(256), 0, stream, (int*)pooled, N_GRAPHS * DIM);

    // ---- CSR build: 2-pass radix ----
    hipLaunchKernelGGL(k_hist, dim3(NEB), dim3(256), 0, stream, dstv, hist);
    hipLaunchKernelGGL(k_reduce, dim3(NCH_HIST), dim3(256), 0, stream, hist, HN, chunk_sums);
    hipLaunchKernelGGL(k_scan_c, dim3(1), dim3(256), 0, stream, chunk_sums, NCH_HIST, hist + HN);
    hipLaunchKernelGGL(k_apply, dim3(NCH_HIST), dim3(256), 0, stream, hist, chunk_sums, hist, HN);
    hipLaunchKernelGGL(k_scatter, dim3(NEB), dim3(256), 0, stream, srcv, dstv, hist, sorted);
    hipLaunchKernelGGL(k_bcount_s, dim3(NBK), dim3(256), 0, stream, hist, sorted, counts);
    hipLaunchKernelGGL(k_reduce, dim3(NCH_CNT), dim3(256), 0, stream, counts, N_NODES, chunk_sums);
    hipLaunchKernelGGL(k_scan_c, dim3(1), dim3(256), 0, stream, chunk_sums, NCH_CNT, row_ptr + N_NODES);
    hipLaunchKernelGGL(k_apply, dim3(NCH_CNT), dim3(256), 0, stream, counts, chunk_sums, row_ptr, N_NODES);
    hipLaunchKernelGGL(k_fill_s, dim3(NBK), dim3(256), 0, stream, hist, sorted, row_ptr, colidx);

    // ---- 3 GIN layers: agg (xb -> hb), mlp (hb -> xb) ----
    dim3 aggGrid((N_NODES + 3) / 4), aggBlk(256);
    dim3 mlpGrid((N_NODES + 63) / 64), mlpBlk(256);
    for (int l = 0; l < 3; l++) {
        hipLaunchKernelGGL(k_agg, aggGrid, aggBlk, 0, stream,
                           (const uint4*)xb, row_ptr, colidx, (uint4*)hb);
        hipLaunchKernelGGL(k_mlp, mlpGrid, mlpBlk, 0, stream,
                           hb, xb, wt + (size_t)(2 * l) * 16384, B1[l],
                           wt + (size_t)(2 * l + 1) * 16384, B2[l]);
    }

    // ---- pool + final ----
    hipLaunchKernelGGL(k_pool, dim3(NPB), dim3(256), 0, stream, (const uint*)xb, batch, pooled);
    hipLaunchKernelGGL(k_final, dim3(N_GRAPHS), dim3(64), 0, stream, pooled, wl, bl, out);
}